// Round 7
// baseline (136.977 us; speedup 1.0000x reference)
//
#include <hip/hip_runtime.h>
#include <stdint.h>

// MSA fused kernel: qkv = z @ W^T ; split heads ; flash attention ; out fp32.
// R10 -> R11 (GEMM only): prefetch double-buffer, BK 64 -> 32.
//   Old loop: barrier -> stage(k) -> barrier+vmcnt(0) -> compute(k): full
//   staging latency exposed every K-step (MfmaUtil 30, VALUBusy 22 -- stall).
//   New loop (attn-style): STAGE(k+1, buf^1) -> compute(k, buf) -> barrier.
//   LDS 48 KB unchanged (3 tensors x 8 KB x 2 bufs) -> 3 blocks/CU unchanged;
//   32 barriers unchanged; staging drains now covered by a compute phase.
//   Buffer index compile-time via x2 unroll (R10 trick). BK=32 chunk swizzle:
//   slot key (l15>>1)&3 -> 2 lanes/bank-quad per quarter (2-way = free).
//   K-chunk order + hi->lo MFMA order preserved -> bit-identical output.
// Also: split+conv merged into one prep kernel (one less launch gap).

typedef _Float16 f16x8 __attribute__((ext_vector_type(8)));
typedef float f32x4 __attribute__((ext_vector_type(4)));
typedef unsigned short u16x8 __attribute__((ext_vector_type(8)));
typedef unsigned short u16x4 __attribute__((ext_vector_type(4)));

#define MFMA_F16(A, B, C) __builtin_amdgcn_mfma_f32_16x16x32_f16((A), (B), (C), 0, 0, 0)

__device__ __forceinline__ unsigned short f2h(float f) {
  _Float16 h = (_Float16)f;  // hw RNE cvt
  return __builtin_bit_cast(unsigned short, h);
}
__device__ __forceinline__ float h2f(unsigned short s) {
  return (float)__builtin_bit_cast(_Float16, s);
}
__device__ __forceinline__ f16x8 ldh8(const unsigned short* p) {
  return __builtin_bit_cast(f16x8, *(const u16x8*)p);
}
// async global->LDS, 16B per lane; dest must be wave-uniform (HW adds lane*16)
__device__ __forceinline__ void lds16(const void* g, void* l) {
  __builtin_amdgcn_global_load_lds((const __attribute__((address_space(1))) void*)g,
                                   (__attribute__((address_space(3))) void*)l,
                                   16, 0, 0);
}

// ---------------- prep: z -> (hi,lo) fp16 ; W -> hi fp16 ----------------
__global__ __launch_bounds__(256) void prep_kernel(
    const float* __restrict__ z, const float* __restrict__ W,
    unsigned short* __restrict__ zh, unsigned short* __restrict__ zl,
    unsigned short* __restrict__ wh, int nz4, int nw4) {
  int i = blockIdx.x * 256 + threadIdx.x;
  if (i < nz4) {
    const float4 v = reinterpret_cast<const float4*>(z)[i];
    float vv[4] = {v.x, v.y, v.z, v.w};
    unsigned short hh[4], ll[4];
#pragma unroll
    for (int j = 0; j < 4; j++) {
      hh[j] = f2h(vv[j]);
      ll[j] = f2h(vv[j] - h2f(hh[j]));
    }
    u16x4 hv = {hh[0], hh[1], hh[2], hh[3]};
    u16x4 lv = {ll[0], ll[1], ll[2], ll[3]};
    *(u16x4*)&zh[i * 4] = hv;
    *(u16x4*)&zl[i * 4] = lv;
  } else {
    const int j = i - nz4;
    if (j < nw4) {
      const float4 v = reinterpret_cast<const float4*>(W)[j];
      u16x4 hv = {f2h(v.x), f2h(v.y), f2h(v.z), f2h(v.w)};
      *(u16x4*)&wh[j * 4] = hv;
    }
  }
}

// ---------------- QKV GEMM: C[4096][3072] = Z @ W^T, scattered epilogue ----------------
// grid (32, 24), 256 threads (4 waves, 2x2, wave-tile 64x64), BK=32, dbuf.
// LDS tiles [128][32] fp16 x2 bufs; 16B chunk c of row r stored at c ^ ((r>>1)&3)
// (pre-swizzled global source, linear LDS dest for global_load_lds).
__global__ __launch_bounds__(256) void qkv_gemm(
    const unsigned short* __restrict__ Ah, const unsigned short* __restrict__ Al,
    const unsigned short* __restrict__ Wh,
    unsigned short* __restrict__ qh, unsigned short* __restrict__ ql,
    unsigned short* __restrict__ kk, unsigned short* __restrict__ vt) {
  __shared__ unsigned short sAh[2][128 * 32], sAl[2][128 * 32], sBh[2][128 * 32];
  const int tid = threadIdx.x;
  const int w = tid >> 6, l = tid & 63;
  const int wr = w >> 1, wc = w & 1;
  const int l15 = l & 15, l4 = l >> 4;
  const int bm = blockIdx.x, bn = blockIdx.y;

  f32x4 acc[4][4];
#pragma unroll
  for (int i = 0; i < 4; i++)
#pragma unroll
    for (int j = 0; j < 4; j++) acc[i][j] = (f32x4){0.f, 0.f, 0.f, 0.f};

  auto STAGE = [&](int bb, int k0) __attribute__((always_inline)) {
#pragma unroll
    for (int c = 0; c < 2; c++) {
      const int chunk = tid + c * 256;          // 0..511: row = chunk/4, chunk-in-row = chunk%4
      const int row = chunk >> 2, cc = chunk & 3;
      const int scc = cc ^ ((row >> 1) & 3);    // pre-swizzled source chunk
      const int aoff = (bm * 128 + row) * 1024 + k0 + scc * 8;
      const int boff = (bn * 128 + row) * 1024 + k0 + scc * 8;
      const int lo = (w * 64 + c * 256) * 8;    // wave-uniform linear LDS dest
      lds16(Ah + aoff, &sAh[bb][lo]);
      lds16(Al + aoff, &sAl[bb][lo]);
      lds16(Wh + boff, &sBh[bb][lo]);
    }
  };

  // one K=32 step from buffer `cur` (literal); prefetch knext into cur^1
  auto gbody = [&](const int cur, const bool pf, const int knext)
      __attribute__((always_inline)) {
    if (pf) STAGE(cur ^ 1, knext);  // in flight across the compute phase
    const int ksl = (l4 ^ ((l15 >> 1) & 3)) * 8;  // swizzled K-slot (2-way free)
    f16x8 afh[4], afl[4], bfr[4];
#pragma unroll
    for (int i = 0; i < 4; i++) {
      const int off = (wr * 64 + i * 16 + l15) * 32 + ksl;
      afh[i] = ldh8(&sAh[cur][off]);
      afl[i] = ldh8(&sAl[cur][off]);
    }
#pragma unroll
    for (int j = 0; j < 4; j++) {
      const int off = (wc * 64 + j * 16 + l15) * 32 + ksl;
      bfr[j] = ldh8(&sBh[cur][off]);
    }
    __builtin_amdgcn_s_setprio(1);
#pragma unroll
    for (int i = 0; i < 4; i++)
#pragma unroll
      for (int j = 0; j < 4; j++) {
        acc[i][j] = MFMA_F16(afh[i], bfr[j], acc[i][j]);
        acc[i][j] = MFMA_F16(afl[i], bfr[j], acc[i][j]);
      }
    __builtin_amdgcn_s_setprio(0);
    __syncthreads();  // vmcnt(0)+lgkmcnt(0)+barrier: prefetched tile visible
  };

  STAGE(0, 0);
  __syncthreads();
#pragma unroll 1
  for (int i2 = 0; i2 < 16; ++i2) {
    gbody(0, true, i2 * 64 + 32);       // K-chunk 2*i2   (buf 0), prefetch odd
    gbody(1, i2 < 15, i2 * 64 + 64);    // K-chunk 2*i2+1 (buf 1), prefetch even
  }

  // epilogue: scatter into q(hi,lo, *0.125*log2e), k(hi), v^T — all fp16
#pragma unroll
  for (int i = 0; i < 4; i++)
#pragma unroll
    for (int j = 0; j < 4; j++)
#pragma unroll
      for (int r = 0; r < 4; r++) {
        float val = acc[i][j][r];
        const int m = bm * 128 + wr * 64 + i * 16 + l4 * 4 + r;
        const int e = bn * 128 + wc * 64 + j * 16 + l15;
        const int b = m >> 11, nidx = m & 2047;
        const int head = e / 192;
        const int rem = e - head * 192;
        const int which = rem >> 6, dh = rem & 63;
        const int bh = b * 16 + head;
        if (which == 0) {
          // 0.125 * log2(e): scores come out in log2 domain -> attn uses exp2
          const float v = val * 0.18033688011112042f;
          const unsigned short h = f2h(v);
          const int o = (bh * 2048 + nidx) * 64 + dh;
          qh[o] = h;
          ql[o] = f2h(v - h2f(h));
        } else if (which == 1) {
          kk[(bh * 2048 + nidx) * 64 + dh] = f2h(val);
        } else {
          vt[(bh * 64 + dh) * 2048 + nidx] = f2h(val);
        }
      }
}

// ---------------- flash attention (no-max softmax, dbuf staging, 16 q-rows/wave) ----
// grid (n/64, b*h) = (32, 32), 256 threads (4 waves); wave w owns q rows
// [q0 + 16w, q0 + 16w + 16). LDS 40 KB, 4 blocks/CU (grid-capped anyway).
// SWAPPED QK^T: S^T = mfma(K, Q) -> lane holds P[q=l15][kv=16t+4*l4+r].
// sP physical slot X = s ^ l15 (s = kv/4): conflict-free write AND read.
// kv loop unrolled x2: compile-time double-buffer index.
__global__ __launch_bounds__(256, 4) void attn_kernel(
    const unsigned short* __restrict__ qh, const unsigned short* __restrict__ ql,
    const unsigned short* __restrict__ kk,
    const unsigned short* __restrict__ vt, float* __restrict__ out) {
  __shared__ unsigned short sK[2][64 * 64], sV[2][64 * 64];
  __shared__ unsigned short sP[4][16 * 64];  // per-wave P tile (16 q x 64 kv)
  const int tid = threadIdx.x, w = tid >> 6, l = tid & 63;
  const int l15 = l & 15, l4 = l >> 4;
  const int swz = l15 & 7;
  const int bh = blockIdx.y;
  const int q0 = blockIdx.x * 64;

  // Q fragments (hi/lo), q pre-scaled by 0.125*log2e
  f16x8 qfh[2], qfl[2];
  {
    const int qrow = (bh * 2048 + q0 + w * 16 + l15) * 64;
#pragma unroll
    for (int kf = 0; kf < 2; kf++) {
      qfh[kf] = ldh8(qh + qrow + kf * 32 + l4 * 8);
      qfl[kf] = ldh8(ql + qrow + kf * 32 + l4 * 8);
    }
  }

  float lsum = 0.f;  // denominator partial for q = l15 (this lane's kv slice)
  f32x4 acc[4];
#pragma unroll
  for (int t = 0; t < 4; t++) acc[t] = (f32x4){0.f, 0.f, 0.f, 0.f};

  const unsigned short* kb = kk + bh * 2048 * 64;
  const unsigned short* vb = vt + bh * 64 * 2048;

  auto STAGE = [&](int bb, int kv0) __attribute__((always_inline)) {
#pragma unroll
    for (int c = 0; c < 2; c++) {
      const int chunk = tid + c * 256;          // 0..511
      const int row = chunk >> 3, cc = chunk & 7;
      const int scc = cc ^ (row & 7);           // pre-swizzled source chunk
      const int lo = (w * 64 + c * 256) * 8;    // wave-uniform linear LDS dest
      lds16(kb + (kv0 + row) * 64 + scc * 8, &sK[bb][lo]);
      lds16(vb + row * 2048 + kv0 + scc * 8, &sV[bb][lo]);
    }
  };

  STAGE(0, 0);
  __syncthreads();

  // one kv tile; cur MUST be a literal so all LDS addressing is static
  auto body = [&](const int cur, const bool pfetch, const int nkv)
      __attribute__((always_inline)) {
    if (pfetch) STAGE(cur ^ 1, nkv);  // prefetch next tile (in flight)

    // S^T = K Q^T (2-term hi/lo): lane: q = l15, kv = 16t + 4*l4 + r
    f32x4 s[4];
    __builtin_amdgcn_s_setprio(1);
#pragma unroll
    for (int t = 0; t < 4; t++) {
      f32x4 z0 = (f32x4){0.f, 0.f, 0.f, 0.f};
#pragma unroll
      for (int kf = 0; kf < 2; kf++) {
        const int off = (t * 16 + l15) * 64 + ((kf * 4 + l4) ^ swz) * 8;
        const f16x8 kh8 = ldh8(&sK[cur][off]);
        z0 = MFMA_F16(kh8, qfh[kf], z0);
        z0 = MFMA_F16(kh8, qfl[kf], z0);
      }
      s[t] = z0;
    }
    __builtin_amdgcn_s_setprio(0);

    // softmax-lite: p = exp2(s); fp32 lsum (denominator rounding residue ~3e-6)
#pragma unroll
    for (int t = 0; t < 4; t++) {
      u16x4 pv;
#pragma unroll
      for (int r = 0; r < 4; r++) {
        const float p = __builtin_amdgcn_exp2f(s[t][r]);
        lsum += p;
        pv[r] = f2h(p);
      }
      const int X = (4 * t + l4) ^ l15;
      *(u16x4*)&sP[w][l15 * 64 + X * 4] = pv;
    }

    // PV: O += P @ V  (A-fragment from two b64 reads at slots s0^l15, (s0^1)^l15)
    __builtin_amdgcn_s_setprio(1);
    f16x8 pf[2];
#pragma unroll
    for (int jf = 0; jf < 2; jf++) {
      const int s0 = 8 * jf + 2 * l4;
      const u16x4 pa = *(const u16x4*)&sP[w][l15 * 64 + (s0 ^ l15) * 4];
      const u16x4 pb = *(const u16x4*)&sP[w][l15 * 64 + ((s0 ^ 1) ^ l15) * 4];
      const u16x8 pcat = {pa[0], pa[1], pa[2], pa[3], pb[0], pb[1], pb[2], pb[3]};
      pf[jf] = __builtin_bit_cast(f16x8, pcat);
    }
#pragma unroll
    for (int t = 0; t < 4; t++)
#pragma unroll
      for (int jf = 0; jf < 2; jf++) {
        const f16x8 vf = ldh8(&sV[cur][(t * 16 + l15) * 64 + ((jf * 4 + l4) ^ swz) * 8]);
        acc[t] = MFMA_F16(pf[jf], vf, acc[t]);
      }
    __builtin_amdgcn_s_setprio(0);

    __syncthreads();  // vmcnt(0)+lgkmcnt(0)+barrier: next tile staged & visible
  };

#pragma unroll 1
  for (int it2 = 0; it2 < 16; ++it2) {
    body(0, true, it2 * 128 + 64);        // tile 2*it2   (buf 0), prefetch odd
    body(1, it2 < 15, it2 * 128 + 128);   // tile 2*it2+1 (buf 1), prefetch even
  }

  // deferred denominator: sum the 4 kv-slices (l4 groups) for each q=l15
  lsum += __shfl_xor(lsum, 16);
  lsum += __shfl_xor(lsum, 32);
  // redistribute: epilogue lane needs lsum of q-row (l4*4+r), held by lane (l4*4+r)
  float ls[4];
#pragma unroll
  for (int r = 0; r < 4; r++) ls[r] = __shfl(lsum, l4 * 4 + r);

  // epilogue: out[b][row][h*64+d] = acc/lsum  (acc: row q = l4*4+r, col d = l15)
  const int b = bh >> 4, h = bh & 15;
#pragma unroll
  for (int t = 0; t < 4; t++)
#pragma unroll
    for (int r = 0; r < 4; r++) {
      const int row = q0 + w * 16 + l4 * 4 + r;
      const int d = t * 16 + l15;
      out[(b * 2048 + row) * 1024 + h * 64 + d] = acc[t][r] / ls[r];
    }
}

extern "C" void kernel_launch(void* const* d_in, const int* in_sizes, int n_in,
                              void* d_out, int out_size, void* d_ws, size_t ws_size,
                              hipStream_t stream) {
  const float* z = (const float*)d_in[0];    // [2,2048,1024]
  const float* Wq = (const float*)d_in[1];   // [3072,1024]
  float* out = (float*)d_out;                // [2,2048,1024]

  const long MK = 4096l * 1024;   // z elems
  const long NK = 3072l * 1024;   // W elems
  const long QS = 2l * 16 * 2048 * 64;  // per q/k/v tensor elems

  char* ws = (char*)d_ws;
  unsigned short* zh = (unsigned short*)ws; ws += MK * 2;
  unsigned short* zl = (unsigned short*)ws; ws += MK * 2;
  unsigned short* wh = (unsigned short*)ws; ws += NK * 2;
  unsigned short* qh = (unsigned short*)ws; ws += QS * 2;
  unsigned short* ql = (unsigned short*)ws; ws += QS * 2;
  unsigned short* kk = (unsigned short*)ws; ws += QS * 2;
  unsigned short* vt = (unsigned short*)ws; ws += QS * 2;

  const int nz4 = (int)(MK / 4), nw4 = (int)(NK / 4);
  prep_kernel<<<(nz4 + nw4 + 255) / 256, 256, 0, stream>>>(z, Wq, zh, zl, wh, nz4, nw4);
  qkv_gemm<<<dim3(32, 24), 256, 0, stream>>>(zh, zl, wh, qh, ql, kk, vt);
  attn_kernel<<<dim3(32, 32), 256, 0, stream>>>(qh, ql, kk, vt, out);
}

// Round 8
// 134.871 us; speedup vs baseline: 1.0156x; 1.0156x over previous
//
#include <hip/hip_runtime.h>
#include <stdint.h>

// MSA fused kernel: qkv = z @ W^T ; split heads ; flash attention ; out fp32.
// R11 -> R12 (GEMM only): fix the prefetch/DS-pipe contention R11 exposed.
//   R11 issued global_load_lds right before the 12 ds_read_b128 -> the DMA
//   writes (same DS pipe) collided with the critical-path LDS reads feeding
//   MFMA (MfmaUtil 30->27, dur 70->79). R12 order per K=32 step:
//     ds_read x12 (cur) -> [sched_barrier] STAGE(next -> cur^1)
//     -> [sched_barrier] 32 MFMAs -> __syncthreads (vmcnt drain)
//   DMA now lands during the register-only MFMA region (no DS contention,
//   ~500+ cyc coverage vs ~200-400 cyc L2 latency; FETCH shows 94% L2/L3 hit).
//   No hazard: reads target cur, DMA targets cur^1. Fragment liveness ~130
//   VGPR -> still 3 waves/SIMD (<=170); pinned with __launch_bounds__(256,3).
//   Numerics bit-identical. Attn (R10) and merged prep unchanged.

typedef _Float16 f16x8 __attribute__((ext_vector_type(8)));
typedef float f32x4 __attribute__((ext_vector_type(4)));
typedef unsigned short u16x8 __attribute__((ext_vector_type(8)));
typedef unsigned short u16x4 __attribute__((ext_vector_type(4)));

#define MFMA_F16(A, B, C) __builtin_amdgcn_mfma_f32_16x16x32_f16((A), (B), (C), 0, 0, 0)

__device__ __forceinline__ unsigned short f2h(float f) {
  _Float16 h = (_Float16)f;  // hw RNE cvt
  return __builtin_bit_cast(unsigned short, h);
}
__device__ __forceinline__ float h2f(unsigned short s) {
  return (float)__builtin_bit_cast(_Float16, s);
}
__device__ __forceinline__ f16x8 ldh8(const unsigned short* p) {
  return __builtin_bit_cast(f16x8, *(const u16x8*)p);
}
// async global->LDS, 16B per lane; dest must be wave-uniform (HW adds lane*16)
__device__ __forceinline__ void lds16(const void* g, void* l) {
  __builtin_amdgcn_global_load_lds((const __attribute__((address_space(1))) void*)g,
                                   (__attribute__((address_space(3))) void*)l,
                                   16, 0, 0);
}

// ---------------- prep: z -> (hi,lo) fp16 ; W -> hi fp16 ----------------
__global__ __launch_bounds__(256) void prep_kernel(
    const float* __restrict__ z, const float* __restrict__ W,
    unsigned short* __restrict__ zh, unsigned short* __restrict__ zl,
    unsigned short* __restrict__ wh, int nz4, int nw4) {
  int i = blockIdx.x * 256 + threadIdx.x;
  if (i < nz4) {
    const float4 v = reinterpret_cast<const float4*>(z)[i];
    float vv[4] = {v.x, v.y, v.z, v.w};
    unsigned short hh[4], ll[4];
#pragma unroll
    for (int j = 0; j < 4; j++) {
      hh[j] = f2h(vv[j]);
      ll[j] = f2h(vv[j] - h2f(hh[j]));
    }
    u16x4 hv = {hh[0], hh[1], hh[2], hh[3]};
    u16x4 lv = {ll[0], ll[1], ll[2], ll[3]};
    *(u16x4*)&zh[i * 4] = hv;
    *(u16x4*)&zl[i * 4] = lv;
  } else {
    const int j = i - nz4;
    if (j < nw4) {
      const float4 v = reinterpret_cast<const float4*>(W)[j];
      u16x4 hv = {f2h(v.x), f2h(v.y), f2h(v.z), f2h(v.w)};
      *(u16x4*)&wh[j * 4] = hv;
    }
  }
}

// ---------------- QKV GEMM: C[4096][3072] = Z @ W^T, scattered epilogue ----------------
// grid (32, 24), 256 threads (4 waves, 2x2, wave-tile 64x64), BK=32, dbuf.
// LDS tiles [128][32] fp16 x2 bufs; 16B chunk c of row r stored at c ^ ((r>>1)&3)
// (pre-swizzled global source, linear LDS dest for global_load_lds).
__global__ __launch_bounds__(256, 3) void qkv_gemm(
    const unsigned short* __restrict__ Ah, const unsigned short* __restrict__ Al,
    const unsigned short* __restrict__ Wh,
    unsigned short* __restrict__ qh, unsigned short* __restrict__ ql,
    unsigned short* __restrict__ kk, unsigned short* __restrict__ vt) {
  __shared__ unsigned short sAh[2][128 * 32], sAl[2][128 * 32], sBh[2][128 * 32];
  const int tid = threadIdx.x;
  const int w = tid >> 6, l = tid & 63;
  const int wr = w >> 1, wc = w & 1;
  const int l15 = l & 15, l4 = l >> 4;
  const int bm = blockIdx.x, bn = blockIdx.y;

  f32x4 acc[4][4];
#pragma unroll
  for (int i = 0; i < 4; i++)
#pragma unroll
    for (int j = 0; j < 4; j++) acc[i][j] = (f32x4){0.f, 0.f, 0.f, 0.f};

  auto STAGE = [&](int bb, int k0) __attribute__((always_inline)) {
#pragma unroll
    for (int c = 0; c < 2; c++) {
      const int chunk = tid + c * 256;          // 0..511: row = chunk/4, chunk-in-row = chunk%4
      const int row = chunk >> 2, cc = chunk & 3;
      const int scc = cc ^ ((row >> 1) & 3);    // pre-swizzled source chunk
      const int aoff = (bm * 128 + row) * 1024 + k0 + scc * 8;
      const int boff = (bn * 128 + row) * 1024 + k0 + scc * 8;
      const int lo = (w * 64 + c * 256) * 8;    // wave-uniform linear LDS dest
      lds16(Ah + aoff, &sAh[bb][lo]);
      lds16(Al + aoff, &sAl[bb][lo]);
      lds16(Wh + boff, &sBh[bb][lo]);
    }
  };

  // one K=32 step from buffer `cur` (literal); prefetch knext into cur^1
  // order: ds_read all 12 -> STAGE (DMA lands under MFMA) -> 32 MFMA -> barrier
  auto gbody = [&](const int cur, const bool pf, const int knext)
      __attribute__((always_inline)) {
    const int ksl = (l4 ^ ((l15 >> 1) & 3)) * 8;  // swizzled K-slot (conflict-free)
    f16x8 afh[4], afl[4], bfr[4];
#pragma unroll
    for (int i = 0; i < 4; i++) {
      const int off = (wr * 64 + i * 16 + l15) * 32 + ksl;
      afh[i] = ldh8(&sAh[cur][off]);
      afl[i] = ldh8(&sAl[cur][off]);
    }
#pragma unroll
    for (int j = 0; j < 4; j++) {
      const int off = (wc * 64 + j * 16 + l15) * 32 + ksl;
      bfr[j] = ldh8(&sBh[cur][off]);
    }
    __builtin_amdgcn_sched_barrier(0);  // pin: reads issued before DMA
    if (pf) STAGE(cur ^ 1, knext);      // in flight across the MFMA region
    __builtin_amdgcn_sched_barrier(0);  // pin: DMA issued before MFMA cluster
    __builtin_amdgcn_s_setprio(1);
#pragma unroll
    for (int i = 0; i < 4; i++)
#pragma unroll
      for (int j = 0; j < 4; j++) {
        acc[i][j] = MFMA_F16(afh[i], bfr[j], acc[i][j]);
        acc[i][j] = MFMA_F16(afl[i], bfr[j], acc[i][j]);
      }
    __builtin_amdgcn_s_setprio(0);
    __syncthreads();  // vmcnt(0)+lgkmcnt(0)+barrier: prefetched tile visible
  };

  STAGE(0, 0);
  __syncthreads();
#pragma unroll 1
  for (int i2 = 0; i2 < 16; ++i2) {
    gbody(0, true, i2 * 64 + 32);       // K-chunk 2*i2   (buf 0), prefetch odd
    gbody(1, i2 < 15, i2 * 64 + 64);    // K-chunk 2*i2+1 (buf 1), prefetch even
  }

  // epilogue: scatter into q(hi,lo, *0.125*log2e), k(hi), v^T — all fp16
#pragma unroll
  for (int i = 0; i < 4; i++)
#pragma unroll
    for (int j = 0; j < 4; j++)
#pragma unroll
      for (int r = 0; r < 4; r++) {
        float val = acc[i][j][r];
        const int m = bm * 128 + wr * 64 + i * 16 + l4 * 4 + r;
        const int e = bn * 128 + wc * 64 + j * 16 + l15;
        const int b = m >> 11, nidx = m & 2047;
        const int head = e / 192;
        const int rem = e - head * 192;
        const int which = rem >> 6, dh = rem & 63;
        const int bh = b * 16 + head;
        if (which == 0) {
          // 0.125 * log2(e): scores come out in log2 domain -> attn uses exp2
          const float v = val * 0.18033688011112042f;
          const unsigned short h = f2h(v);
          const int o = (bh * 2048 + nidx) * 64 + dh;
          qh[o] = h;
          ql[o] = f2h(v - h2f(h));
        } else if (which == 1) {
          kk[(bh * 2048 + nidx) * 64 + dh] = f2h(val);
        } else {
          vt[(bh * 64 + dh) * 2048 + nidx] = f2h(val);
        }
      }
}

// ---------------- flash attention (no-max softmax, dbuf staging, 16 q-rows/wave) ----
// grid (n/64, b*h) = (32, 32), 256 threads (4 waves); wave w owns q rows
// [q0 + 16w, q0 + 16w + 16). LDS 40 KB, 4 blocks/CU (grid-capped anyway).
// SWAPPED QK^T: S^T = mfma(K, Q) -> lane holds P[q=l15][kv=16t+4*l4+r].
// sP physical slot X = s ^ l15 (s = kv/4): conflict-free write AND read.
// kv loop unrolled x2: compile-time double-buffer index.
__global__ __launch_bounds__(256, 4) void attn_kernel(
    const unsigned short* __restrict__ qh, const unsigned short* __restrict__ ql,
    const unsigned short* __restrict__ kk,
    const unsigned short* __restrict__ vt, float* __restrict__ out) {
  __shared__ unsigned short sK[2][64 * 64], sV[2][64 * 64];
  __shared__ unsigned short sP[4][16 * 64];  // per-wave P tile (16 q x 64 kv)
  const int tid = threadIdx.x, w = tid >> 6, l = tid & 63;
  const int l15 = l & 15, l4 = l >> 4;
  const int swz = l15 & 7;
  const int bh = blockIdx.y;
  const int q0 = blockIdx.x * 64;

  // Q fragments (hi/lo), q pre-scaled by 0.125*log2e
  f16x8 qfh[2], qfl[2];
  {
    const int qrow = (bh * 2048 + q0 + w * 16 + l15) * 64;
#pragma unroll
    for (int kf = 0; kf < 2; kf++) {
      qfh[kf] = ldh8(qh + qrow + kf * 32 + l4 * 8);
      qfl[kf] = ldh8(ql + qrow + kf * 32 + l4 * 8);
    }
  }

  float lsum = 0.f;  // denominator partial for q = l15 (this lane's kv slice)
  f32x4 acc[4];
#pragma unroll
  for (int t = 0; t < 4; t++) acc[t] = (f32x4){0.f, 0.f, 0.f, 0.f};

  const unsigned short* kb = kk + bh * 2048 * 64;
  const unsigned short* vb = vt + bh * 64 * 2048;

  auto STAGE = [&](int bb, int kv0) __attribute__((always_inline)) {
#pragma unroll
    for (int c = 0; c < 2; c++) {
      const int chunk = tid + c * 256;          // 0..511
      const int row = chunk >> 3, cc = chunk & 7;
      const int scc = cc ^ (row & 7);           // pre-swizzled source chunk
      const int lo = (w * 64 + c * 256) * 8;    // wave-uniform linear LDS dest
      lds16(kb + (kv0 + row) * 64 + scc * 8, &sK[bb][lo]);
      lds16(vb + row * 2048 + kv0 + scc * 8, &sV[bb][lo]);
    }
  };

  STAGE(0, 0);
  __syncthreads();

  // one kv tile; cur MUST be a literal so all LDS addressing is static
  auto body = [&](const int cur, const bool pfetch, const int nkv)
      __attribute__((always_inline)) {
    if (pfetch) STAGE(cur ^ 1, nkv);  // prefetch next tile (in flight)

    // S^T = K Q^T (2-term hi/lo): lane: q = l15, kv = 16t + 4*l4 + r
    f32x4 s[4];
    __builtin_amdgcn_s_setprio(1);
#pragma unroll
    for (int t = 0; t < 4; t++) {
      f32x4 z0 = (f32x4){0.f, 0.f, 0.f, 0.f};
#pragma unroll
      for (int kf = 0; kf < 2; kf++) {
        const int off = (t * 16 + l15) * 64 + ((kf * 4 + l4) ^ swz) * 8;
        const f16x8 kh8 = ldh8(&sK[cur][off]);
        z0 = MFMA_F16(kh8, qfh[kf], z0);
        z0 = MFMA_F16(kh8, qfl[kf], z0);
      }
      s[t] = z0;
    }
    __builtin_amdgcn_s_setprio(0);

    // softmax-lite: p = exp2(s); fp32 lsum (denominator rounding residue ~3e-6)
#pragma unroll
    for (int t = 0; t < 4; t++) {
      u16x4 pv;
#pragma unroll
      for (int r = 0; r < 4; r++) {
        const float p = __builtin_amdgcn_exp2f(s[t][r]);
        lsum += p;
        pv[r] = f2h(p);
      }
      const int X = (4 * t + l4) ^ l15;
      *(u16x4*)&sP[w][l15 * 64 + X * 4] = pv;
    }

    // PV: O += P @ V  (A-fragment from two b64 reads at slots s0^l15, (s0^1)^l15)
    __builtin_amdgcn_s_setprio(1);
    f16x8 pf[2];
#pragma unroll
    for (int jf = 0; jf < 2; jf++) {
      const int s0 = 8 * jf + 2 * l4;
      const u16x4 pa = *(const u16x4*)&sP[w][l15 * 64 + (s0 ^ l15) * 4];
      const u16x4 pb = *(const u16x4*)&sP[w][l15 * 64 + ((s0 ^ 1) ^ l15) * 4];
      const u16x8 pcat = {pa[0], pa[1], pa[2], pa[3], pb[0], pb[1], pb[2], pb[3]};
      pf[jf] = __builtin_bit_cast(f16x8, pcat);
    }
#pragma unroll
    for (int t = 0; t < 4; t++)
#pragma unroll
      for (int jf = 0; jf < 2; jf++) {
        const f16x8 vf = ldh8(&sV[cur][(t * 16 + l15) * 64 + ((jf * 4 + l4) ^ swz) * 8]);
        acc[t] = MFMA_F16(pf[jf], vf, acc[t]);
      }
    __builtin_amdgcn_s_setprio(0);

    __syncthreads();  // vmcnt(0)+lgkmcnt(0)+barrier: next tile staged & visible
  };

#pragma unroll 1
  for (int it2 = 0; it2 < 16; ++it2) {
    body(0, true, it2 * 128 + 64);        // tile 2*it2   (buf 0), prefetch odd
    body(1, it2 < 15, it2 * 128 + 128);   // tile 2*it2+1 (buf 1), prefetch even
  }

  // deferred denominator: sum the 4 kv-slices (l4 groups) for each q=l15
  lsum += __shfl_xor(lsum, 16);
  lsum += __shfl_xor(lsum, 32);
  // redistribute: epilogue lane needs lsum of q-row (l4*4+r), held by lane (l4*4+r)
  float ls[4];
#pragma unroll
  for (int r = 0; r < 4; r++) ls[r] = __shfl(lsum, l4 * 4 + r);

  // epilogue: out[b][row][h*64+d] = acc/lsum  (acc: row q = l4*4+r, col d = l15)
  const int b = bh >> 4, h = bh & 15;
#pragma unroll
  for (int t = 0; t < 4; t++)
#pragma unroll
    for (int r = 0; r < 4; r++) {
      const int row = q0 + w * 16 + l4 * 4 + r;
      const int d = t * 16 + l15;
      out[(b * 2048 + row) * 1024 + h * 64 + d] = acc[t][r] / ls[r];
    }
}

extern "C" void kernel_launch(void* const* d_in, const int* in_sizes, int n_in,
                              void* d_out, int out_size, void* d_ws, size_t ws_size,
                              hipStream_t stream) {
  const float* z = (const float*)d_in[0];    // [2,2048,1024]
  const float* Wq = (const float*)d_in[1];   // [3072,1024]
  float* out = (float*)d_out;                // [2,2048,1024]

  const long MK = 4096l * 1024;   // z elems
  const long NK = 3072l * 1024;   // W elems
  const long QS = 2l * 16 * 2048 * 64;  // per q/k/v tensor elems

  char* ws = (char*)d_ws;
  unsigned short* zh = (unsigned short*)ws; ws += MK * 2;
  unsigned short* zl = (unsigned short*)ws; ws += MK * 2;
  unsigned short* wh = (unsigned short*)ws; ws += NK * 2;
  unsigned short* qh = (unsigned short*)ws; ws += QS * 2;
  unsigned short* ql = (unsigned short*)ws; ws += QS * 2;
  unsigned short* kk = (unsigned short*)ws; ws += QS * 2;
  unsigned short* vt = (unsigned short*)ws; ws += QS * 2;

  const int nz4 = (int)(MK / 4), nw4 = (int)(NK / 4);
  prep_kernel<<<(nz4 + nw4 + 255) / 256, 256, 0, stream>>>(z, Wq, zh, zl, wh, nz4, nw4);
  qkv_gemm<<<dim3(32, 24), 256, 0, stream>>>(zh, zl, wh, qh, ql, kk, vt);
  attn_kernel<<<dim3(32, 32), 256, 0, stream>>>(qh, ql, kk, vt, out);
}